// Round 9
// baseline (179.461 us; speedup 1.0000x reference)
//
#include <hip/hip_runtime.h>
#include <hip/hip_bf16.h>
#include <stdint.h>

typedef unsigned short u16;
typedef short short8 __attribute__((ext_vector_type(8)));
typedef short short4v __attribute__((ext_vector_type(4)));
typedef float floatx4 __attribute__((ext_vector_type(4)));

__device__ __forceinline__ float b2f(u16 v) {
  union { unsigned int u; float f; } c; c.u = ((unsigned int)v) << 16; return c.f;
}
__device__ __forceinline__ u16 f2b(float f) {
  union { float f; unsigned int u; } c; c.f = f;
  unsigned int u = c.u;
  return (u16)((u + 0x7fffu + ((u >> 16) & 1u)) >> 16);  // RNE
}
// packed f32x2 -> bf16x2 (RNE), single HW instr (no builtin on gfx950)
__device__ __forceinline__ unsigned int cvtpk_bf16(float lo, float hi) {
  unsigned int r;
  asm("v_cvt_pk_bf16_f32 %0, %1, %2" : "=v"(r) : "v"(lo), "v"(hi));
  return r;
}

// async global->LDS, 16B per lane. LDS dest must be wave-uniform base + lane*16.
__device__ __forceinline__ void gld_lds16(const u16* g, u16* l) {
  __builtin_amdgcn_global_load_lds(
      (const __attribute__((address_space(1))) unsigned int*)g,
      (__attribute__((address_space(3))) unsigned int*)l,
      16, 0, 0);
}

// ---------------------------------------------------------------------------
// Fused prep (R16: conversion blocks fattened 8x for ILP / fewer launches):
// x fp32->bf16 (blocks 0..767, 8 chunks each), w_attn T (768..1199),
// w_proj T (1200..1343). Transposes also convert fp32->bf16.
// ---------------------------------------------------------------------------
__device__ __forceinline__ void tile_transpose_f2b(
    const float* __restrict__ in, u16* __restrict__ out,
    int inRS, int outRS, int rb, int cb, int tid)
{
  __shared__ __align__(16) u16 t[64][72];
  const int r = tid >> 2, sg = tid & 3;
  const float* ip = in + (long)(rb + r) * inRS + cb + sg * 16;
#pragma unroll
  for (int i = 0; i < 16; i += 4) {
    float4 f = *(const float4*)(ip + i);
    t[r][sg * 16 + i]     = f2b(f.x);
    t[r][sg * 16 + i + 1] = f2b(f.y);
    t[r][sg * 16 + i + 2] = f2b(f.z);
    t[r][sg * 16 + i + 3] = f2b(f.w);
  }
  __syncthreads();
  short8 v0, v1;
#pragma unroll
  for (int i = 0; i < 8; i++) v0[i] = (short)t[sg * 16 + i][r];
#pragma unroll
  for (int i = 0; i < 8; i++) v1[i] = (short)t[sg * 16 + 8 + i][r];
  *(short8*)(out + (long)(cb + r) * outRS + rb + sg * 16)     = v0;
  *(short8*)(out + (long)(cb + r) * outRS + rb + sg * 16 + 8) = v1;
}

__global__ __launch_bounds__(256) void prep(
    const float* __restrict__ x, u16* __restrict__ xb,
    const float* __restrict__ w_attn, u16* __restrict__ wTa,
    const float* __restrict__ w_proj, u16* __restrict__ wTp)
{
  const int bid = blockIdx.x, tid = threadIdx.x;
  if (bid < 768) {
    // 768 blocks x 8 chunks x 256 thr x 4 floats = 8192*768
#pragma unroll
    for (int k = 0; k < 8; k++) {
      int i = (bid * 2048 + k * 256 + tid) * 4;
      float4 f = *(const float4*)(x + i);
      short4v v;
      v[0] = (short)f2b(f.x); v[1] = (short)f2b(f.y);
      v[2] = (short)f2b(f.z); v[3] = (short)f2b(f.w);
      *(short4v*)(xb + i) = v;
    }
  } else if (bid < 1200) {
    int t = bid - 768;                  // 36 x 12 tiles of w_attn [768][2304]
    tile_transpose_f2b(w_attn, wTa, 2304, 768, (t / 36) * 64, (t % 36) * 64, tid);
  } else {
    int t = bid - 1200;                 // 12 x 12 tiles of w_proj [768][768]
    tile_transpose_f2b(w_proj, wTp, 768, 768, (t / 12) * 64, (t % 12) * 64, tid);
  }
}

// ---------------------------------------------------------------------------
// qkv GEMM — R11 version VERBATIM (measured 44.6-45.5 us across 3 rounds).
// ---------------------------------------------------------------------------
#define QKV_K 768
#define QKV_NT 24   // 768/32
#define VMW(n) asm volatile("s_waitcnt vmcnt(" #n ")" ::: "memory")

__global__ __launch_bounds__(768, 3) void gemm_qkv_288(
    const u16* __restrict__ A, const u16* __restrict__ Bt,
    const float* __restrict__ bias, u16* __restrict__ qkOut, u16* __restrict__ vT)
{
  __shared__ __align__(16) u16 sA[4][256 * 32];   // 64 KiB
  __shared__ __align__(16) u16 sB[4][288 * 32];   // 72 KiB

  const int bid = blockIdx.x;
  const int wg = (bid & 7) * 32 + (bid >> 3);
  const int bx = wg & 7;        // col tile 0..7 (288 cols each)
  const int by = wg >> 3;       // row tile 0..31 (256 rows each)

  const int tid = threadIdx.x;
  const int lane = tid & 63;
  const int l15 = lane & 15, q = lane >> 4;
  const int wave = tid >> 6;          // 0..11
  const int wm = (wave / 6) * 128;    // 2 M-groups
  const int wn = (wave % 6) * 48;     // 6 N-groups (3 frags each)
  const long rowbase = (long)by * 256;
  const long colbase = (long)bx * 288;
  const int xq = ((q ^ ((l15 >> 1) & 3)) << 3);   // swizzled k-octet (u16)

  const int cA0 = tid, cA1 = 768 + tid;   // A: 1024 chunks (waves 0-3 take 2nd)
  const int cB0 = tid, cB1 = 768 + tid;   // B: 1152 chunks (waves 0-5 take 2nd)
  const u16* pa0 = A + (rowbase + (cA0 >> 2)) * QKV_K + ((((cA0 & 3) ^ ((cA0 >> 3) & 3))) << 3);
  const u16* pa1 = A + (rowbase + (cA1 >> 2)) * QKV_K + ((((cA1 & 3) ^ ((cA1 >> 3) & 3))) << 3);
  const u16* pb0 = Bt + (colbase + (cB0 >> 2)) * QKV_K + ((((cB0 & 3) ^ ((cB0 >> 3) & 3))) << 3);
  const u16* pb1 = Bt + (colbase + (cB1 >> 2)) * QKV_K + ((((cB1 & 3) ^ ((cB1 >> 3) & 3))) << 3);
  const bool hasA1 = (tid < 256);   // wave-uniform (waves 0-3)
  const bool hasB1 = (tid < 384);   // wave-uniform (waves 0-5)

#define STAGE(t, s) do { \
    const long k0_ = (long)(t) * 32; \
    gld_lds16(pa0 + k0_, &sA[s][cA0 * 8]); \
    if (hasA1) gld_lds16(pa1 + k0_, &sA[s][cA1 * 8]); \
    gld_lds16(pb0 + k0_, &sB[s][cB0 * 8]); \
    if (hasB1) gld_lds16(pb1 + k0_, &sB[s][cB1 * 8]); } while (0)

  floatx4 acc[8][3];
#pragma unroll
  for (int i = 0; i < 8; i++)
#pragma unroll
    for (int n = 0; n < 3; n++) acc[i][n] = (floatx4){0.f, 0.f, 0.f, 0.f};

  STAGE(0, 0); STAGE(1, 1); STAGE(2, 2);
  if (wave < 4) VMW(8); else if (wave < 6) VMW(6); else VMW(4);
  __builtin_amdgcn_s_barrier();   // all waves' tile-0 resident

#pragma unroll 4
  for (int j = 0; j < QKV_NT; ++j) {
    const int slot = j & 3;
    const u16* ap = sA[slot];
    const u16* bp = sB[slot];

    // phase A: 7 ds_reads, stage tile j+3, 12 MFMA
    short8 bf[3];
#pragma unroll
    for (int nt = 0; nt < 3; nt++)
      bf[nt] = *(const short8*)(bp + (wn + nt * 16 + l15) * 32 + xq);
    short8 af[4];
#pragma unroll
    for (int mt = 0; mt < 4; mt++)
      af[mt] = *(const short8*)(ap + (wm + mt * 16 + l15) * 32 + xq);
    if (j + 3 < QKV_NT) STAGE(j + 3, (j + 3) & 3);
    __builtin_amdgcn_s_setprio(1);
#pragma unroll
    for (int mt = 0; mt < 4; mt++)
#pragma unroll
      for (int nt = 0; nt < 3; nt++)
        acc[mt][nt] = __builtin_amdgcn_mfma_f32_16x16x32_bf16(af[mt], bf[nt], acc[mt][nt], 0, 0, 0);
    __builtin_amdgcn_s_setprio(0);

    // phase B: 4 ds_reads, 12 MFMA
#pragma unroll
    for (int mt = 0; mt < 4; mt++)
      af[mt] = *(const short8*)(ap + (wm + 64 + mt * 16 + l15) * 32 + xq);
    __builtin_amdgcn_s_setprio(1);
#pragma unroll
    for (int mt = 0; mt < 4; mt++)
#pragma unroll
      for (int nt = 0; nt < 3; nt++)
        acc[4 + mt][nt] = __builtin_amdgcn_mfma_f32_16x16x32_bf16(af[mt], bf[nt], acc[4 + mt][nt], 0, 0, 0);
    __builtin_amdgcn_s_setprio(0);

    // boundary: tile j+1 resident; counted waits, wave-uniform, never 0 mid-loop
    if (j < QKV_NT - 1) {
      if (j + 3 < QKV_NT) {
        if (wave < 4) VMW(8); else if (wave < 6) VMW(6); else VMW(4);
      } else if (j + 2 < QKV_NT) {
        if (wave < 4) VMW(4); else if (wave < 6) VMW(3); else VMW(2);
      } else {
        VMW(0);
      }
      __builtin_amdgcn_s_barrier();
    }
  }
#undef STAGE

  // epilogue: per-fragment split at col 1536
#pragma unroll
  for (int nt = 0; nt < 3; nt++) {
    const int fragc = (int)colbase + wn + nt * 16;   // lane-invariant, 16-aligned
    const int col = fragc + l15;
    const float bv = bias[col];
    if (fragc >= 1536) {
      const long bb = rowbase >> 10;
      const int dloc = col - 1536;
      u16* op = vT + (bb * 12 + (dloc >> 6)) * 65536L + (long)(dloc & 63) * 1024;
      const int t0 = (int)(rowbase & 1023) + wm;
#pragma unroll
      for (int mt = 0; mt < 8; mt++) {
        short4v pv;
#pragma unroll
        for (int r = 0; r < 4; r++) pv[r] = (short)f2b(acc[mt][nt][r] + bv);
        *(short4v*)(op + t0 + mt * 16 + q * 4) = pv;
      }
    } else {
#pragma unroll
      for (int mt = 0; mt < 8; mt++)
#pragma unroll
        for (int r = 0; r < 4; r++) {
          const long row = rowbase + wm + mt * 16 + q * 4 + r;
          qkOut[row * 1536 + col] = f2b(acc[mt][nt][r] + bv);
        }
    }
  }
}

// ---------------------------------------------------------------------------
// proj GEMM — R14 version VERBATIM (not in top-5 => below attn/qkv).
// ---------------------------------------------------------------------------
__global__ __launch_bounds__(768, 3) void gemm_proj_96(
    const u16* __restrict__ A, const u16* __restrict__ Bt,
    const float* __restrict__ bias, float* __restrict__ C)
{
  __shared__ __align__(16) u16 sA[4][256 * 32];   // 64 KiB
  __shared__ __align__(16) u16 sB[4][96 * 32];    // 24 KiB

  const int bid = blockIdx.x;
  const int wg = (bid & 7) * 32 + (bid >> 3);
  const int bx = wg & 7;        // col tile 0..7 (96 cols each)
  const int by = wg >> 3;       // row tile 0..31 (256 rows each)

  const int tid = threadIdx.x;
  const int lane = tid & 63;
  const int l15 = lane & 15, q = lane >> 4;
  const int wave = tid >> 6;          // 0..11
  const int wm = (wave / 3) * 64;     // 4 M-groups (4 m-frags each)
  const int wn = (wave % 3) * 32;     // 3 N-groups (2 n-frags each)
  const long rowbase = (long)by * 256;
  const long colbase = (long)bx * 96;
  const int xq = ((q ^ ((l15 >> 1) & 3)) << 3);   // swizzled k-octet (u16)

  const int cA0 = tid, cA1 = 768 + tid;
  const int cB0 = (tid < 384) ? tid : (tid - 384);   // clamp unused in-range
  const u16* pa0 = A + (rowbase + (cA0 >> 2)) * 768 + ((((cA0 & 3) ^ ((cA0 >> 3) & 3))) << 3);
  const u16* pa1 = A + (rowbase + (cA1 >> 2)) * 768 + ((((cA1 & 3) ^ ((cA1 >> 3) & 3))) << 3);
  const u16* pb0 = Bt + (colbase + (cB0 >> 2)) * 768 + ((((cB0 & 3) ^ ((cB0 >> 3) & 3))) << 3);
  const bool hasA1 = (tid < 256);   // waves 0-3
  const bool hasB0 = (tid < 384);   // waves 0-5

#define PSTAGE(t, s) do { \
    const long k0_ = (long)(t) * 32; \
    gld_lds16(pa0 + k0_, &sA[s][cA0 * 8]); \
    if (hasA1) gld_lds16(pa1 + k0_, &sA[s][cA1 * 8]); \
    if (hasB0) gld_lds16(pb0 + k0_, &sB[s][cB0 * 8]); } while (0)

  floatx4 acc[4][2];
#pragma unroll
  for (int i = 0; i < 4; i++)
#pragma unroll
    for (int n = 0; n < 2; n++) acc[i][n] = (floatx4){0.f, 0.f, 0.f, 0.f};

  PSTAGE(0, 0); PSTAGE(1, 1); PSTAGE(2, 2);
  if (wave < 4) VMW(6); else if (wave < 6) VMW(4); else VMW(2);
  __builtin_amdgcn_s_barrier();

#pragma unroll 4
  for (int j = 0; j < QKV_NT; ++j) {
    const int slot = j & 3;
    const u16* ap = sA[slot];
    const u16* bp = sB[slot];

    short8 bf[2], af[4];
#pragma unroll
    for (int nt = 0; nt < 2; nt++)
      bf[nt] = *(const short8*)(bp + (wn + nt * 16 + l15) * 32 + xq);
#pragma unroll
    for (int mt = 0; mt < 4; mt++)
      af[mt] = *(const short8*)(ap + (wm + mt * 16 + l15) * 32 + xq);
    if (j + 3 < QKV_NT) PSTAGE(j + 3, (j + 3) & 3);
    __builtin_amdgcn_s_setprio(1);
#pragma unroll
    for (int mt = 0; mt < 4; mt++)
#pragma unroll
      for (int nt = 0; nt < 2; nt++)
        acc[mt][nt] = __builtin_amdgcn_mfma_f32_16x16x32_bf16(af[mt], bf[nt], acc[mt][nt], 0, 0, 0);
    __builtin_amdgcn_s_setprio(0);

    if (j < QKV_NT - 1) {
      if (j + 3 < QKV_NT) {
        if (wave < 4) VMW(6); else if (wave < 6) VMW(4); else VMW(2);
      } else if (j + 2 < QKV_NT) {
        if (wave < 4) VMW(3); else if (wave < 6) VMW(2); else VMW(1);
      } else {
        VMW(0);
      }
      __builtin_amdgcn_s_barrier();
    }
  }
#undef PSTAGE

#pragma unroll
  for (int nt = 0; nt < 2; nt++) {
    const int col = (int)colbase + wn + nt * 16 + l15;
    const float bv = bias[col];
#pragma unroll
    for (int mt = 0; mt < 4; mt++)
#pragma unroll
      for (int r = 0; r < 4; r++) {
        const long row = rowbase + wm + mt * 16 + q * 4 + r;
        C[row * 768 + col] = acc[mt][nt][r] + bv;
      }
  }
}
#undef VMW

// ---------------------------------------------------------------------------
// R16 flash attention: R15 (64-row, exp2+cvt_pk+defer-max) + T14 async-STAGE:
// next tile's K/V global loads are ISSUED before QK^T (into registers) and
// COMMITTED to LDS after the mid-barrier -- the ~500-900cy HBM/L2 latency
// hides under QK^T+softmax instead of serializing at the loop top.
// Barrier structure unchanged (2/iter):
//   iter j: issue loads(j+1); QK(j)[sK]; softmax->sP; SYNC1 (QK reads done,
//   sP visible); write sK(j+1), sV[(j+1)&1]; rescale; PV(j)[sV[j&1],sP];
//   SYNC2 (writes visible for QK(j+1); sP reads done).
// ---------------------------------------------------------------------------
__global__ __launch_bounds__(256) void attn_fwd(
    const u16* __restrict__ qk, const u16* __restrict__ vT, u16* __restrict__ y)
{
  const int bh = blockIdx.x;        // b*12 + h
  const int qt = 15 - blockIdx.y;   // reversed: long blocks dispatch first
  const int b = bh / 12, h = bh % 12;
  const long rowOff = (long)b * 1024;
  const int qb = qt * 64;

  __shared__ __align__(16) u16 sK[64 * 72];
  __shared__ __align__(16) u16 sV[2][64 * 72];  // V^T [d][key], double-buffered
  __shared__ __align__(16) u16 sP[64 * 72];     // P [qrow][key]

  const int tid = threadIdx.x;
  const int lane = tid & 63, wave = tid >> 6;
  const int l15 = lane & 15, q = lane >> 4;
  const int qrow_g = qb + wave * 16 + l15;    // this lane's softmax row

  const u16* kBase = qk + rowOff * 1536 + 768 + (long)h * 64;  // K rows, stride 1536
  const u16* vBase = vT + (long)bh * 65536;                    // V^T rows d, stride 1024

  // Q fragments, pre-scaled by (1/8)*log2(e) => scores land in log2 domain
  short8 qf[2];
  {
    const float qs = 0.125f * 1.44269504f;
    const u16* qp = qk + (long)(rowOff + qrow_g) * 1536 + h * 64 + q * 8;
    short8 a0 = *(const short8*)(qp);
    short8 a1 = *(const short8*)(qp + 32);
#pragma unroll
    for (int i = 0; i < 8; i++) {
      a0[i] = (short)f2b(b2f((u16)a0[i]) * qs);
      a1[i] = (short)f2b(b2f((u16)a1[i]) * qs);
    }
    qf[0] = a0; qf[1] = a1;
  }

  float m_i = -1e30f, l_i = 0.f;
  floatx4 o[4];
#pragma unroll
  for (int nt = 0; nt < 4; nt++) o[nt] = (floatx4){0.f, 0.f, 0.f, 0.f};

  // prologue: tile 0 -> sK, sV[0]
#pragma unroll
  for (int rep = 0; rep < 2; rep++) {
    int idx = tid + rep * 256;
    int r = idx >> 3, ch = (idx & 7) * 8;
    *(short8*)(sK + r * 72 + ch)    = *(const short8*)(kBase + (long)r * 1536 + ch);
    *(short8*)(sV[0] + r * 72 + ch) = *(const short8*)(vBase + (long)r * 1024 + ch);
  }
  __syncthreads();

  for (int j = 0; j <= qt; j++) {
    const int jb = j * 64;
    u16* sVc = sV[j & 1];

    // T14: issue next tile's global loads NOW (hide latency under QK+softmax)
    short8 rk[2], rv[2];
    if (j < qt) {
#pragma unroll
      for (int rep = 0; rep < 2; rep++) {
        int idx = tid + rep * 256;
        int r = idx >> 3, ch = (idx & 7) * 8;
        rk[rep] = *(const short8*)(kBase + (long)(jb + 64 + r) * 1536 + ch);
        rv[rep] = *(const short8*)(vBase + (long)r * 1024 + (jb + 64) + ch);
      }
    }

    floatx4 sf[4];
#pragma unroll
    for (int mt = 0; mt < 4; mt++) sf[mt] = (floatx4){0.f, 0.f, 0.f, 0.f};
#pragma unroll
    for (int kk = 0; kk < 2; kk++) {
#pragma unroll
      for (int mt = 0; mt < 4; mt++) {
        short8 kf = *(const short8*)(sK + (mt * 16 + l15) * 72 + kk * 32 + q * 8);
        sf[mt] = __builtin_amdgcn_mfma_f32_16x16x32_bf16(kf, qf[kk], sf[mt], 0, 0, 0);
      }
    }

    // causal mask + tile max (log2 domain)
    float tmx = -1e30f;
#pragma unroll
    for (int mt = 0; mt < 4; mt++)
#pragma unroll
      for (int r = 0; r < 4; r++) {
        int key_g = jb + mt * 16 + q * 4 + r;
        float v = sf[mt][r];
        if (key_g > qrow_g) v = -1e30f;
        sf[mt][r] = v;
        tmx = fmaxf(tmx, v);
      }
    tmx = fmaxf(tmx, __shfl_xor(tmx, 16));
    tmx = fmaxf(tmx, __shfl_xor(tmx, 32));

    // defer-max: skip rescale when all rows' growth <= 8 (P bounded by 256)
    const bool defer = __all(tmx <= m_i + 8.0f);
    float al = 1.0f;
    float mx = m_i;
    if (!defer) {
      mx = fmaxf(m_i, tmx);
      al = __builtin_amdgcn_exp2f(m_i - mx);
      m_i = mx;
    }

    float rsum = 0.f;
#pragma unroll
    for (int mt = 0; mt < 4; mt++) {
      float p0 = __builtin_amdgcn_exp2f(sf[mt][0] - mx);
      float p1 = __builtin_amdgcn_exp2f(sf[mt][1] - mx);
      float p2 = __builtin_amdgcn_exp2f(sf[mt][2] - mx);
      float p3 = __builtin_amdgcn_exp2f(sf[mt][3] - mx);
      rsum += (p0 + p1) + (p2 + p3);
      unsigned int w0 = cvtpk_bf16(p0, p1);
      unsigned int w1 = cvtpk_bf16(p2, p3);
      uint2 pw; pw.x = w0; pw.y = w1;
      *(uint2*)(sP + (wave * 16 + l15) * 72 + mt * 16 + q * 4) = pw;
    }
    rsum += __shfl_xor(rsum, 16);
    rsum += __shfl_xor(rsum, 32);
    l_i = l_i * al + rsum;
    __syncthreads();   // SYNC1: sP visible; all QK reads of sK(j) done

    // commit next tile to LDS (loads long since landed; sK reads are done,
    // sV writes target the other buffer)
    if (j < qt) {
#pragma unroll
      for (int rep = 0; rep < 2; rep++) {
        int idx = tid + rep * 256;
        int r = idx >> 3, ch = (idx & 7) * 8;
        *(short8*)(sK + r * 72 + ch)              = rk[rep];
        *(short8*)(sV[(j + 1) & 1] + r * 72 + ch) = rv[rep];
      }
    }

    if (!defer) {
      float al_r[4];
#pragma unroll
      for (int r = 0; r < 4; r++) al_r[r] = __shfl(al, q * 4 + r);
#pragma unroll
      for (int nt = 0; nt < 4; nt++)
#pragma unroll
        for (int r = 0; r < 4; r++) o[nt][r] *= al_r[r];
    }
#pragma unroll
    for (int kk = 0; kk < 2; kk++) {
      short8 pf = *(const short8*)(sP + (wave * 16 + l15) * 72 + kk * 32 + q * 8);
#pragma unroll
      for (int nt = 0; nt < 4; nt++) {
        short8 vf = *(const short8*)(sVc + (nt * 16 + l15) * 72 + kk * 32 + q * 8);
        o[nt] = __builtin_amdgcn_mfma_f32_16x16x32_bf16(pf, vf, o[nt], 0, 0, 0);
      }
    }
    __syncthreads();   // SYNC2: sK/sV(j+1) visible; sP(j) reads done
  }

  float linv = 1.f / l_i;
  float li_r[4];
#pragma unroll
  for (int r = 0; r < 4; r++) li_r[r] = __shfl(linv, q * 4 + r);
#pragma unroll
  for (int nt = 0; nt < 4; nt++)
#pragma unroll
    for (int r = 0; r < 4; r++) {
      int row = qb + wave * 16 + q * 4 + r;
      int col = h * 64 + nt * 16 + l15;
      y[(rowOff + row) * 768 + col] = f2b(o[nt][r] * li_r[r]);
    }
}

// ---------------------------------------------------------------------------
extern "C" void kernel_launch(void* const* d_in, const int* in_sizes, int n_in,
                              void* d_out, int out_size, void* d_ws, size_t ws_size,
                              hipStream_t stream) {
  const float* x      = (const float*)d_in[0];  // [8192][768] fp32
  const float* w_attn = (const float*)d_in[1];  // [768][2304] fp32
  const float* b_attn = (const float*)d_in[2];  // [2304] fp32
  const float* w_proj = (const float*)d_in[3];  // [768][768] fp32
  const float* b_proj = (const float*)d_in[4];  // [768] fp32
  float* out = (float*)d_out;                   // [8192][768] fp32

  char* ws = (char*)d_ws;
  u16* xb   = (u16*)ws; ws += (size_t)8192 * 768 * 2;     // 12.6 MB
  u16* wTa  = (u16*)ws; ws += (size_t)2304 * 768 * 2;     //  3.5 MB
  u16* wTp  = (u16*)ws; ws += (size_t)768 * 768 * 2;      //  1.2 MB
  u16* qk   = (u16*)ws; ws += (size_t)8192 * 1536 * 2;    // 25.2 MB (Q|K)
  u16* vT   = (u16*)ws; ws += (size_t)96 * 64 * 1024 * 2; // 12.6 MB (V^T)
  u16* yatt = (u16*)ws; ws += (size_t)8192 * 768 * 2;     // 12.6 MB

  // fused prep: x->bf16 (fat blocks) + both weight transposes
  prep<<<dim3(1344), 256, 0, stream>>>(x, xb, w_attn, wTa, w_proj, wTp);

  // qkv GEMM: R11 verbatim
  gemm_qkv_288<<<dim3(256), 768, 0, stream>>>(xb, wTa, b_attn, qk, vT);

  // flash attention: 64-row tiles, slim softmax + T14 async-STAGE
  attn_fwd<<<dim3(96, 16), 256, 0, stream>>>(qk, vT, yatt);

  // proj GEMM: 256x96 tiles, grid 256 = 1/CU, qkv-class pipeline
  gemm_proj_96<<<dim3(256), 768, 0, stream>>>(yatt, wTp, b_proj, out);
}